// Round 6
// baseline (108.963 us; speedup 1.0000x reference)
//
#include <hip/hip_runtime.h>
#include <hip/hip_cooperative_groups.h>
#include <stdint.h>

// MajFC: out[b,c] = 2.25 * sum_g clip(sum_{k<3} sign(x[b,3g+k])*sign(w[c,3g+k]), -1, 1)
// Sign-only bitplanes (absmax 0.0 verified): t = px ^ pw,
// clip(group) = 1 - 2*maj(t0,t1,t2), out = 2304 - 4.5*popc_total.
//
// Permutation trick: element e = 768q + 12l + 3j + k -> plane [q][3j+k] bit l,
// applied identically to x and w rows, leaves the popc-sum invariant.
//
// R14: cooperative single dispatch = the only structure with compulsory traffic.
// Evidence trail: R10-R13 showed every self-contained-tile design pays >=196 MB
// redundant raw reads (grid>=256 constraint), served at L3 rate (~7 TB/s) ->
// ~29 µs kernel regardless of ordering tricks (R13's K-phasing: null, blocks
// drift out of phase). Fix the STRUCTURE: pack all 1280 rows ONCE (15.7 MB),
// grid.sync() (cooperative API - harness-supported; the old "~60 µs fence"
// datum was hand-rolled spin-fences, needs direct test), then consume packed
// planes (6 MB L3 reads). Predicted kernel ~8-12 µs, total ~58-63.

namespace cg = cooperative_groups;

#define C_IN  3072
#define C_OUT 1024
#define BT 32
#define CT 32
#define PSTR 49   // u64 per packed LDS row: 48 planes + 1 pad (stride 392 B -> 2-way, free)

// pk layout in ws: [1280 rows][48 u64]; rows 0..255 = x, 256..1279 = w.

__device__ __forceinline__ void pack_job(int j, const float* __restrict__ x,
                                         const float* __restrict__ w,
                                         uint64_t* __restrict__ pk, int lane) {
    const int row = j >> 2;
    const int q   = j & 3;
    const float* src = ((row < 256) ? (x + (size_t)row * C_IN)
                                    : (w + (size_t)(row - 256) * C_IN))
                       + q * 768 + 12 * lane;
    const float4* s4 = (const float4*)src;
    float4 f0 = s4[0], f1 = s4[1], f2 = s4[2];
    uint64_t pl0  = __ballot(f0.x > 0.0f);
    uint64_t pl1  = __ballot(f0.y > 0.0f);
    uint64_t pl2  = __ballot(f0.z > 0.0f);
    uint64_t pl3  = __ballot(f0.w > 0.0f);
    uint64_t pl4  = __ballot(f1.x > 0.0f);
    uint64_t pl5  = __ballot(f1.y > 0.0f);
    uint64_t pl6  = __ballot(f1.z > 0.0f);
    uint64_t pl7  = __ballot(f1.w > 0.0f);
    uint64_t pl8  = __ballot(f2.x > 0.0f);
    uint64_t pl9  = __ballot(f2.y > 0.0f);
    uint64_t pl10 = __ballot(f2.z > 0.0f);
    uint64_t pl11 = __ballot(f2.w > 0.0f);
    if (lane == 0) {
        uint64_t* d = pk + (size_t)row * 48 + q * 12;
        d[0] = pl0;  d[1] = pl1;  d[2]  = pl2;  d[3]  = pl3;
        d[4] = pl4;  d[5] = pl5;  d[6]  = pl6;  d[7]  = pl7;
        d[8] = pl8;  d[9] = pl9;  d[10] = pl10; d[11] = pl11;
    }
}

__global__ __launch_bounds__(1024) void majfc_coop(const float* __restrict__ x,
                                                   const float* __restrict__ w,
                                                   uint64_t* __restrict__ pk,
                                                   float* __restrict__ out) {
    __shared__ uint64_t xp[BT][PSTR];
    __shared__ uint64_t wp[CT][PSTR];

    const int tid  = threadIdx.x;
    const int lane = tid & 63;
    const int wv   = tid >> 6;                 // 0..15
    const int W    = blockIdx.x * 16 + wv;     // global wave 0..4095

    // ---- phase 1: 5120 chunk-jobs (1280 rows x 4 K-quarters), each row packed
    // exactly once grid-wide. Consecutive waves take consecutive q-chunks ->
    // dense contiguous coverage, zero redundancy (15.7 MB compulsory read).
    pack_job(W, x, w, pk, lane);
    if (W < 1024) pack_job(W + 4096, x, w, pk, lane);

    cg::this_grid().sync();   // on-GPU barrier + device-scope memory visibility

    // ---- phase 2: tile 32b x 32c per block (XCD-aware map), stage packed
    // rows 24 KB/block from ws (6 MB grid-wide, L2/L3), popc-majority.
    const int r  = blockIdx.x & 7;
    const int s  = blockIdx.x >> 3;
    const int ct = r * 4 + (s & 3);
    const int bt = s >> 2;
    const int b0 = bt * BT;
    const int c0 = ct * CT;

#pragma unroll
    for (int i = 0; i < 3; ++i) {
        const int p   = tid + i * 1024;        // 0..3071 over [64 rows][48]
        const int row = p / 48;
        const int m   = p - row * 48;
        if (row < 32) xp[row][m]      = pk[(size_t)(b0 + row) * 48 + m];
        else          wp[row - 32][m] = pk[(size_t)(256 + c0 + row - 32) * 48 + m];
    }
    __syncthreads();

    const int cl = tid & 31;
    const int bl = tid >> 5;
    int acc = 0;
#pragma unroll
    for (int q = 0; q < 4; ++q) {
        uint64_t X[12], Wr[12];
#pragma unroll
        for (int m = 0; m < 12; ++m) {
            X[m]  = xp[bl][q * 12 + m];        // half-wave-uniform broadcast
            Wr[m] = wp[cl][q * 12 + m];        // 2-way bank alias (free)
        }
#pragma unroll
        for (int j = 0; j < 4; ++j) {
            uint64_t t0 = X[3 * j + 0] ^ Wr[3 * j + 0];
            uint64_t t1 = X[3 * j + 1] ^ Wr[3 * j + 1];
            uint64_t t2 = X[3 * j + 2] ^ Wr[3 * j + 2];
            acc += __popcll((t0 & t1) | (t2 & (t0 | t1)));
        }
    }
    out[(size_t)(b0 + bl) * C_OUT + c0 + cl] = 2304.0f - 4.5f * (float)acc;
}

extern "C" void kernel_launch(void* const* d_in, const int* in_sizes, int n_in,
                              void* d_out, int out_size, void* d_ws, size_t ws_size,
                              hipStream_t stream) {
    const float* x = (const float*)d_in[0];   // [256, 3072] f32
    const float* w = (const float*)d_in[1];   // [1024, 3072] f32
    float* out = (float*)d_out;               // [256, 1024] f32
    uint64_t* pk = (uint64_t*)d_ws;           // 1280*48*8 = 491520 B

    void* args[] = {(void*)&x, (void*)&w, (void*)&pk, (void*)&out};
    hipLaunchCooperativeKernel((void*)majfc_coop, dim3(256), dim3(1024),
                               args, 0, stream);
}

// Round 7
// 69.209 us; speedup vs baseline: 1.5744x; 1.5744x over previous
//
#include <hip/hip_runtime.h>
#include <stdint.h>

// MajFC: out[b,c] = 2.25 * sum_g clip(sum_{k<3} sign(x[b,3g+k])*sign(w[c,3g+k]), -1, 1)
// Sign-only bitplanes (absmax 0.0 verified): t = px ^ pw,
// clip(group) = 1 - 2*maj(t0,t1,t2), out = 2304 - 4.5*popc_total.
//
// Permutation trick: element e = 768q + 12l + 3j + k -> plane [q][3j+k] bit l,
// applied identically to x and w rows, leaves the popc-sum invariant.
//
// R15: structure space now fully mapped ->
//   - redundant-tile single dispatch: >=196 MB structural L3 traffic, ~29 µs (R10-R13)
//   - grid.sync cooperative: barrier alone ~50 µs (R14)
//   - two-dispatch (R8, 70.3 total = 47 harness + ~23 GPU) wins; its sink was
//     maj_main re-reading wpk PER-LANE x128 blocks = 48 MB L2/L3 @ 8 waves/CU.
// R15 = R8's exactly-once pack (15.7 MB compulsory, 5120 one-shot waves) +
// R11's proven consume phase as dispatch 2: 32b x 32c tiles staging PACKED
// planes via LDS -> 24 KB/block, 6 MB grid-wide (8x less traffic), 16 waves/CU.
// Predicted: pack 3-4 µs + maj 2-3 µs + bubble -> total ~55-61.

#define C_IN  3072
#define C_OUT 1024
#define BT 32
#define CT 32
#define PSTR 49   // u64 LDS row stride: 48 planes + 1 pad (392 B -> 2-way bank alias, free)

// pk layout in ws: [1280 rows][48 u64]; rows 0..255 = x, 256..1279 = w.

__global__ __launch_bounds__(256) void pack_signs(const float* __restrict__ x,
                                                  const float* __restrict__ w,
                                                  uint64_t* __restrict__ pk) {
    const int j    = blockIdx.x * 4 + (threadIdx.x >> 6);   // chunk-job 0..5119
    const int lane = threadIdx.x & 63;
    const int row  = j >> 2;
    const int q    = j & 3;
    const float* src = ((row < 256) ? (x + (size_t)row * C_IN)
                                    : (w + (size_t)(row - 256) * C_IN))
                       + q * 768 + 12 * lane;
    const float4* s4 = (const float4*)src;
    float4 f0 = s4[0], f1 = s4[1], f2 = s4[2];
    uint64_t pl0  = __ballot(f0.x > 0.0f);
    uint64_t pl1  = __ballot(f0.y > 0.0f);
    uint64_t pl2  = __ballot(f0.z > 0.0f);
    uint64_t pl3  = __ballot(f0.w > 0.0f);
    uint64_t pl4  = __ballot(f1.x > 0.0f);
    uint64_t pl5  = __ballot(f1.y > 0.0f);
    uint64_t pl6  = __ballot(f1.z > 0.0f);
    uint64_t pl7  = __ballot(f1.w > 0.0f);
    uint64_t pl8  = __ballot(f2.x > 0.0f);
    uint64_t pl9  = __ballot(f2.y > 0.0f);
    uint64_t pl10 = __ballot(f2.z > 0.0f);
    uint64_t pl11 = __ballot(f2.w > 0.0f);
    if (lane == 0) {
        uint64_t* d = pk + (size_t)row * 48 + q * 12;
        d[0] = pl0;  d[1] = pl1;  d[2]  = pl2;  d[3]  = pl3;
        d[4] = pl4;  d[5] = pl5;  d[6]  = pl6;  d[7]  = pl7;
        d[8] = pl8;  d[9] = pl9;  d[10] = pl10; d[11] = pl11;
    }
}

// ---- consume: 256 blocks x 1024 threads, tile = 32b x 32c (R11-proven phase) --
__global__ __launch_bounds__(1024) void maj_main(const uint64_t* __restrict__ pk,
                                                 float* __restrict__ out) {
    __shared__ uint64_t xp[BT][PSTR];
    __shared__ uint64_t wp[CT][PSTR];

    const int tid = threadIdx.x;

    // XCD-aware tile map (bijective): r=bid&7 -> ct=r*4+(s&3), bt=s>>2
    const int r  = blockIdx.x & 7;
    const int s  = blockIdx.x >> 3;
    const int ct = r * 4 + (s & 3);
    const int bt = s >> 2;
    const int b0 = bt * BT;
    const int c0 = ct * CT;

    // stage 24 KB of packed planes: [64 combined rows][48 u64], coalesced
#pragma unroll
    for (int i = 0; i < 3; ++i) {
        const int p   = tid + i * 1024;        // 0..3071
        const int row = p / 48;
        const int m   = p - row * 48;
        if (row < 32) xp[row][m]      = pk[(size_t)(b0 + row) * 48 + m];
        else          wp[row - 32][m] = pk[(size_t)(256 + c0 + row - 32) * 48 + m];
    }
    __syncthreads();

    // thread = (b_local = tid>>5, c_local = tid&31)
    // X: 2-address broadcast per wave; W: 2-way bank alias (free, PSTR=49).
    const int cl = tid & 31;
    const int bl = tid >> 5;
    int acc = 0;
#pragma unroll
    for (int q = 0; q < 4; ++q) {
        uint64_t X[12], Wr[12];
#pragma unroll
        for (int m = 0; m < 12; ++m) {
            X[m]  = xp[bl][q * 12 + m];
            Wr[m] = wp[cl][q * 12 + m];
        }
#pragma unroll
        for (int j = 0; j < 4; ++j) {
            uint64_t t0 = X[3 * j + 0] ^ Wr[3 * j + 0];
            uint64_t t1 = X[3 * j + 1] ^ Wr[3 * j + 1];
            uint64_t t2 = X[3 * j + 2] ^ Wr[3 * j + 2];
            acc += __popcll((t0 & t1) | (t2 & (t0 | t1)));
        }
    }
    out[(size_t)(b0 + bl) * C_OUT + c0 + cl] = 2304.0f - 4.5f * (float)acc;
}

extern "C" void kernel_launch(void* const* d_in, const int* in_sizes, int n_in,
                              void* d_out, int out_size, void* d_ws, size_t ws_size,
                              hipStream_t stream) {
    const float* x = (const float*)d_in[0];   // [256, 3072] f32
    const float* w = (const float*)d_in[1];   // [1024, 3072] f32
    float* out = (float*)d_out;               // [256, 1024] f32
    uint64_t* pk = (uint64_t*)d_ws;           // 1280*48*8 = 491520 B

    pack_signs<<<1280, 256, 0, stream>>>(x, w, pk);
    maj_main<<<256, 1024, 0, stream>>>(pk, out);
}